// Round 4
// baseline (5961.335 us; speedup 1.0000x reference)
//
#include <hip/hip_runtime.h>
#include <hip/hip_bf16.h>

typedef __hip_bfloat16 bf16;

#define B_  4
#define NT_ 1024
#define NS_ 1024
#define D_  512
#define E_  512
#define H_  8
#define HD_ 64
#define FF_ 2048
#define RH_ 16

__device__ int g_flag;   // 0 = bf16 tensors, 1 = fp32 tensors

__device__ __forceinline__ float b2f(bf16 x) { return __bfloat162float(x); }

__device__ __forceinline__ float2 upair(unsigned int u) {
  union { unsigned int i; float f; } lo, hi;
  lo.i = u << 16;
  hi.i = u & 0xffff0000u;
  return make_float2(lo.f, hi.f);
}

__device__ __forceinline__ unsigned short f2b_bits(float f) {
  union { bf16 h; unsigned short s; } u;
  u.h = __float2bfloat16(f);
  return u.s;
}

__device__ __forceinline__ unsigned int packbf(float a, float b) {
  return (unsigned int)f2b_bits(a) | ((unsigned int)f2b_bits(b) << 16);
}

template <typename T> struct TypeTag;
template <> struct TypeTag<float> { static constexpr int v = 1; };
template <> struct TypeTag<bf16>  { static constexpr int v = 0; };

template <typename T> __device__ __forceinline__ float ld1(const T* p);
template <> __device__ __forceinline__ float ld1<float>(const float* p) { return *p; }
template <> __device__ __forceinline__ float ld1<bf16>(const bf16* p) { return b2f(*p); }

template <typename T> __device__ __forceinline__ float2 ld2(const T* p);
template <> __device__ __forceinline__ float2 ld2<float>(const float* p) { return *(const float2*)p; }
template <> __device__ __forceinline__ float2 ld2<bf16>(const bf16* p) { return upair(*(const unsigned int*)p); }

template <typename T> __device__ __forceinline__ void st2(T* p, float a, float b);
template <> __device__ __forceinline__ void st2<float>(float* p, float a, float b) { *(float2*)p = make_float2(a, b); }
template <> __device__ __forceinline__ void st2<bf16>(bf16* p, float a, float b) { *(unsigned int*)p = packbf(a, b); }

// ---- detector: fp32 inputs leave random-exponent garbage when read as bf16 ---
__global__ void detect_kernel(const unsigned int* __restrict__ xt_raw) {
  __shared__ int bad;
  if (threadIdx.x == 0) bad = 0;
  __syncthreads();
  int t = threadIdx.x;
  int local = 0;
  for (int i = 0; i < 8; ++i) {
    float2 v = upair(xt_raw[t * 8 + i]);
    if (!(fabsf(v.x) <= 1e8f)) local = 1;
    if (!(fabsf(v.y) <= 1e8f)) local = 1;
  }
  if (local) atomicOr(&bad, 1);
  __syncthreads();
  if (t == 0) g_flag = bad;
}

// ---------------- RPE part 1: b_emb (needed by attention) ---------------------
template <typename T>
__global__ void rpe_bemb_kernel(const T* __restrict__ coords,
                                const T* __restrict__ W1, const T* __restrict__ b1,
                                const T* __restrict__ W2, T* __restrict__ b_emb) {
  if (g_flag != TypeTag<T>::v) return;
  __shared__ float sW1[32], sb1[16], sW2[128];
  int tid = threadIdx.x;
  if (tid < 32)  sW1[tid] = ld1(W1 + tid);
  if (tid < 16)  sb1[tid] = ld1(b1 + tid);
  if (tid < 128) sW2[tid] = ld1(W2 + tid);
  __syncthreads();
  size_t idx = (size_t)blockIdx.x * 256 + tid;
  float2 c = ld2(coords + idx * 2);
  float h[16];
#pragma unroll
  for (int j = 0; j < 16; ++j) {
    float t = fmaf(c.x, sW1[j], fmaf(c.y, sW1[16 + j], sb1[j]));
    h[j] = t > 0.f ? t : 0.f;
  }
  float acc[8] = {0.f, 0.f, 0.f, 0.f, 0.f, 0.f, 0.f, 0.f};
#pragma unroll
  for (int j = 0; j < 16; ++j) {
    float hv = h[j];
#pragma unroll
    for (int n = 0; n < 8; ++n) acc[n] = fmaf(hv, sW2[j * 8 + n], acc[n]);
  }
  T* bp = b_emb + idx * 8;
#pragma unroll
  for (int j = 0; j < 4; ++j) st2(bp + 2 * j, acc[2 * j], acc[2 * j + 1]);
}

// ---------------- RPE part 2: rel_emb (runs LAST; overwrites scratch) ---------
template <typename T>
__global__ void rpe_rel_kernel(const T* __restrict__ coords,
                               const T* __restrict__ W1, const T* __restrict__ b1,
                               T* __restrict__ rel_emb) {
  if (g_flag != TypeTag<T>::v) return;
  __shared__ float sW1[32], sb1[16];
  int tid = threadIdx.x;
  if (tid < 32)  sW1[tid] = ld1(W1 + tid);
  if (tid < 16)  sb1[tid] = ld1(b1 + tid);
  __syncthreads();
  size_t idx = (size_t)blockIdx.x * 256 + tid;
  float2 c = ld2(coords + idx * 2);
  T* rp = rel_emb + idx * 16;
#pragma unroll
  for (int j = 0; j < 16; j += 2) {
    float t0 = fmaf(c.x, sW1[j], fmaf(c.y, sW1[16 + j], sb1[j]));
    float t1 = fmaf(c.x, sW1[j + 1], fmaf(c.y, sW1[16 + j + 1], sb1[j + 1]));
    st2(rp + j, t0 > 0.f ? t0 : 0.f, t1 > 0.f ? t1 : 0.f);
  }
}

// ---------------- projection + per-head normalize (+scale for q) --------------
// mode: 0 = v, 1 = k (normalize), 2 = q (normalize * exp(min(ls,log100)))
template <typename T>
__global__ void proj_kernel(const T* __restrict__ X, const T* __restrict__ W,
                            const T* __restrict__ bias, const T* __restrict__ lsc,
                            float* __restrict__ out, int mode) {
  if (g_flag != TypeTag<T>::v) return;
  __shared__ float xrow[512];
  __shared__ float orow[512];
  __shared__ float hs[8];
  int tid = threadIdx.x;
  int m = blockIdx.x;
  {
    float2 xv = ld2(X + (size_t)m * 512 + 2 * tid);
    xrow[2 * tid] = xv.x;
    xrow[2 * tid + 1] = xv.y;
  }
  __syncthreads();
  int n0 = 2 * tid;
  float acc0 = 0.f, acc1 = 0.f;
#pragma unroll 4
  for (int k = 0; k < 512; ++k) {
    float xv = xrow[k];
    float2 wv = ld2(W + (size_t)k * 512 + n0);
    acc0 = fmaf(xv, wv.x, acc0);
    acc1 = fmaf(xv, wv.y, acc1);
  }
  {
    float2 bv = ld2(bias + n0);
    acc0 += bv.x;
    acc1 += bv.y;
  }
  if (mode > 0) {
    orow[n0] = acc0;
    orow[n0 + 1] = acc1;
    __syncthreads();
    if (tid < 8) {
      float s = 0.f;
      for (int i = 0; i < 64; ++i) { float t = orow[tid * 64 + i]; s = fmaf(t, t, s); }
      float r = 1.0f / sqrtf(s + 1e-12f);
      if (mode == 2) r *= expf(fminf(ld1(lsc + tid), 4.60517018598809f));
      hs[tid] = r;
    }
    __syncthreads();
    float r = hs[n0 >> 6];
    acc0 *= r;
    acc1 *= r;
  }
  int b = m >> 10, row = m & 1023;
  int hh = n0 >> 6, d = n0 & 63;
  float* op = out + ((((size_t)b * H_ + hh) * 1024 + row) * 64 + d);
  *(float2*)op = make_float2(acc0, acc1);
}

// ---------------- attention: one block per (b,h,q) row ------------------------
template <typename T>
__global__ void attn_kernel(const float* __restrict__ qn, const float* __restrict__ kn,
                            const float* __restrict__ vv, const T* __restrict__ bemb,
                            T* __restrict__ att, float* __restrict__ ctx) {
  if (g_flag != TypeTag<T>::v) return;
  __shared__ float qrow[64];
  __shared__ float sc[1024];
  __shared__ float red[256];
  int tid = threadIdx.x;
  int h = blockIdx.x, q = blockIdx.y, b = blockIdx.z;
  size_t bh = (size_t)b * H_ + h;
  const float* qp = qn + (bh * 1024 + q) * 64;
  if (tid < 64) qrow[tid] = qp[tid];
  __syncthreads();
  const float* kbase = kn + bh * 1024 * 64;
  const T* bb = bemb + (((size_t)b * 1024 + q) * 1024) * 8 + h;
  float loc[4];
#pragma unroll
  for (int i = 0; i < 4; ++i) {
    int kk = i * 256 + tid;
    const float* kr = kbase + (size_t)kk * 64;
    float acc = 0.f;
#pragma unroll
    for (int d = 0; d < 64; d += 4) {
      float4 qv = *(const float4*)(qrow + d);
      float4 kv = *(const float4*)(kr + d);
      acc = fmaf(qv.x, kv.x, acc);
      acc = fmaf(qv.y, kv.y, acc);
      acc = fmaf(qv.z, kv.z, acc);
      acc = fmaf(qv.w, kv.w, acc);
    }
    acc += ld1(bb + (size_t)kk * 8);
    sc[kk] = acc;
    loc[i] = acc;
  }
  float mx = fmaxf(fmaxf(loc[0], loc[1]), fmaxf(loc[2], loc[3]));
  red[tid] = mx;
  __syncthreads();
  for (int s = 128; s > 0; s >>= 1) {
    if (tid < s) red[tid] = fmaxf(red[tid], red[tid + s]);
    __syncthreads();
  }
  mx = red[0];
  __syncthreads();
  float psum = 0.f;
#pragma unroll
  for (int i = 0; i < 4; ++i) {
    int kk = i * 256 + tid;
    float p = expf(sc[kk] - mx);
    sc[kk] = p;
    psum += p;
  }
  red[tid] = psum;
  __syncthreads();
  for (int s = 128; s > 0; s >>= 1) {
    if (tid < s) red[tid] += red[tid + s];
    __syncthreads();
  }
  float inv = 1.0f / red[0];
  __syncthreads();
#pragma unroll
  for (int i = 0; i < 4; ++i) {
    int kk = i * 256 + tid;
    sc[kk] *= inv;
  }
  __syncthreads();
  T* ap = att + (bh * 1024 + q) * 1024;
#pragma unroll
  for (int i = 0; i < 2; ++i) {
    int n0 = i * 512 + 2 * tid;
    st2(ap + n0, sc[n0], sc[n0 + 1]);
  }
  // PV
  const float* vb = vv + bh * 1024 * 64;
  int part = tid >> 6, d = tid & 63;
  float acc = 0.f;
  for (int k = part * 256; k < part * 256 + 256; ++k)
    acc = fmaf(sc[k], vb[(size_t)k * 64 + d], acc);
  red[tid] = acc;
  __syncthreads();
  if (tid < 64) {
    float c = red[tid] + red[64 + tid] + red[128 + tid] + red[192 + tid];
    ctx[((size_t)b * 1024 + q) * 512 + h * 64 + tid] = c;
  }
}

// ---------------- out-proj + bias + residual + LayerNorm1 ---------------------
template <typename T>
__global__ void oproj_ln(const float* __restrict__ ctx, const T* __restrict__ Wo,
                         const T* __restrict__ bo, const T* __restrict__ xt,
                         const T* __restrict__ g, const T* __restrict__ bta,
                         float* __restrict__ xout) {
  if (g_flag != TypeTag<T>::v) return;
  __shared__ float xrow[512];
  __shared__ float red[256];
  int tid = threadIdx.x, m = blockIdx.x;
  *(float2*)(xrow + 2 * tid) = *(const float2*)(ctx + (size_t)m * 512 + 2 * tid);
  __syncthreads();
  int n0 = 2 * tid;
  float acc0 = 0.f, acc1 = 0.f;
#pragma unroll 4
  for (int k = 0; k < 512; ++k) {
    float xv = xrow[k];
    float2 wv = ld2(Wo + (size_t)k * 512 + n0);
    acc0 = fmaf(xv, wv.x, acc0);
    acc1 = fmaf(xv, wv.y, acc1);
  }
  float2 bv = ld2(bo + n0);
  float2 xv = ld2(xt + (size_t)m * 512 + n0);
  float x0 = acc0 + bv.x + xv.x;
  float x1 = acc1 + bv.y + xv.y;
  red[tid] = x0 + x1;
  __syncthreads();
  for (int s = 128; s > 0; s >>= 1) {
    if (tid < s) red[tid] += red[tid + s];
    __syncthreads();
  }
  float mu = red[0] * (1.0f / 512.0f);
  __syncthreads();
  float d0 = x0 - mu, d1 = x1 - mu;
  red[tid] = d0 * d0 + d1 * d1;
  __syncthreads();
  for (int s = 128; s > 0; s >>= 1) {
    if (tid < s) red[tid] += red[tid + s];
    __syncthreads();
  }
  float rstd = 1.0f / sqrtf(red[0] * (1.0f / 512.0f) + 1e-5f);
  float2 gv = ld2(g + n0);
  float2 btv = ld2(bta + n0);
  float* op = xout + (size_t)m * 512 + n0;
  op[0] = d0 * rstd * gv.x + btv.x;
  op[1] = d1 * rstd * gv.y + btv.y;
}

// ---------------- fused MLP + residual + LN2 -> out ---------------------------
template <typename T>
__global__ void mlp_fused(const float* __restrict__ xin, const T* __restrict__ W1,
                          const T* __restrict__ b1, const T* __restrict__ W2,
                          const T* __restrict__ b2, const T* __restrict__ g,
                          const T* __restrict__ bt, T* __restrict__ out) {
  if (g_flag != TypeTag<T>::v) return;
  __shared__ float xrow[512];
  __shared__ float hrow[2048];
  __shared__ float red[256];
  int tid = threadIdx.x, m = blockIdx.x;
  *(float2*)(xrow + 2 * tid) = *(const float2*)(xin + (size_t)m * 512 + 2 * tid);
  __syncthreads();
  float acc[8] = {0.f, 0.f, 0.f, 0.f, 0.f, 0.f, 0.f, 0.f};
#pragma unroll 2
  for (int k = 0; k < 512; ++k) {
    float xv = xrow[k];
    const T* wr = W1 + (size_t)k * 2048;
#pragma unroll
    for (int j = 0; j < 4; ++j) {
      float2 wv = ld2(wr + 2 * tid + j * 512);
      acc[2 * j] = fmaf(xv, wv.x, acc[2 * j]);
      acc[2 * j + 1] = fmaf(xv, wv.y, acc[2 * j + 1]);
    }
  }
#pragma unroll
  for (int j = 0; j < 4; ++j) {
    int n = 2 * tid + j * 512;
    float2 bv = ld2(b1 + n);
    float r0 = acc[2 * j] + bv.x;
    float r1 = acc[2 * j + 1] + bv.y;
    hrow[n] = r0 > 0.f ? r0 : 0.f;
    hrow[n + 1] = r1 > 0.f ? r1 : 0.f;
  }
  __syncthreads();
  int n0 = 2 * tid;
  float y0 = 0.f, y1 = 0.f;
#pragma unroll 4
  for (int k = 0; k < 2048; ++k) {
    float hv = hrow[k];
    float2 wv = ld2(W2 + (size_t)k * 512 + n0);
    y0 = fmaf(hv, wv.x, y0);
    y1 = fmaf(hv, wv.y, y1);
  }
  float2 bv = ld2(b2 + n0);
  y0 += bv.x; y1 += bv.y;
  y0 = y0 > 0.f ? y0 : 0.f;
  y1 = y1 > 0.f ? y1 : 0.f;
  float x0 = xrow[n0] + y0;
  float x1 = xrow[n0 + 1] + y1;
  red[tid] = x0 + x1;
  __syncthreads();
  for (int s = 128; s > 0; s >>= 1) {
    if (tid < s) red[tid] += red[tid + s];
    __syncthreads();
  }
  float mu = red[0] * (1.0f / 512.0f);
  __syncthreads();
  float d0 = x0 - mu, d1 = x1 - mu;
  red[tid] = d0 * d0 + d1 * d1;
  __syncthreads();
  for (int s = 128; s > 0; s >>= 1) {
    if (tid < s) red[tid] += red[tid + s];
    __syncthreads();
  }
  float rstd = 1.0f / sqrtf(red[0] * (1.0f / 512.0f) + 1e-5f);
  float2 gv = ld2(g + n0);
  float2 btv = ld2(bt + n0);
  st2(out + (size_t)m * 512 + n0, d0 * rstd * gv.x + btv.x, d1 * rstd * gv.y + btv.y);
}

extern "C" void kernel_launch(void* const* d_in, const int* in_sizes, int n_in,
                              void* d_out, int out_size, void* d_ws, size_t ws_size,
                              hipStream_t stream) {
  // element offsets into d_out (same for either dtype)
  const size_t OFF_X = 0, OFF_ATT = 2097152, OFF_REL = 35651584, OFF_BEMB = 102760448;

  float* outf = (float*)d_out;
  bf16*  outb = (bf16*)d_out;

  // Scratch: inside the rel_emb region under BOTH dtype interpretations.
  // fp32: rel region = bytes [142606336, 411041792)  -> scratch 40MB fits
  // bf16: rel region = bytes [71303168, 205520896)   -> scratch at 142.6MB +40MB fits
  float* scratch = (float*)((char*)d_out + 142606336);
  float* qn   = scratch;
  float* kn   = qn + 2097152;
  float* vvp  = kn + 2097152;
  float* ctx  = vvp + 2097152;
  float* xln1 = ctx + 2097152;

  detect_kernel<<<1, 256, 0, stream>>>((const unsigned int*)d_in[1]);

#define ARGS_BEMB(T, OP) (const T*)d_in[2], (const T*)d_in[12], (const T*)d_in[13], (const T*)d_in[14], OP + OFF_BEMB
  rpe_bemb_kernel<bf16><<<dim3((B_ * NT_ * NS_) / 256), 256, 0, stream>>>(ARGS_BEMB(bf16, outb));
  rpe_bemb_kernel<float><<<dim3((B_ * NT_ * NS_) / 256), 256, 0, stream>>>(ARGS_BEMB(float, outf));

#define ARGS_Q(T) (const T*)d_in[1], (const T*)d_in[3], (const T*)d_in[4], (const T*)d_in[11], qn, 2
#define ARGS_K(T) (const T*)d_in[0], (const T*)d_in[5], (const T*)d_in[6], (const T*)d_in[11], kn, 1
#define ARGS_V(T) (const T*)d_in[0], (const T*)d_in[7], (const T*)d_in[8], (const T*)d_in[11], vvp, 0
  proj_kernel<bf16><<<dim3(B_ * NT_), 256, 0, stream>>>(ARGS_Q(bf16));
  proj_kernel<float><<<dim3(B_ * NT_), 256, 0, stream>>>(ARGS_Q(float));
  proj_kernel<bf16><<<dim3(B_ * NS_), 256, 0, stream>>>(ARGS_K(bf16));
  proj_kernel<float><<<dim3(B_ * NS_), 256, 0, stream>>>(ARGS_K(float));
  proj_kernel<bf16><<<dim3(B_ * NS_), 256, 0, stream>>>(ARGS_V(bf16));
  proj_kernel<float><<<dim3(B_ * NS_), 256, 0, stream>>>(ARGS_V(float));

  attn_kernel<bf16><<<dim3(H_, NT_, B_), 256, 0, stream>>>(qn, kn, vvp, outb + OFF_BEMB, outb + OFF_ATT, ctx);
  attn_kernel<float><<<dim3(H_, NT_, B_), 256, 0, stream>>>(qn, kn, vvp, outf + OFF_BEMB, outf + OFF_ATT, ctx);

#define ARGS_O(T) ctx, (const T*)d_in[9], (const T*)d_in[10], (const T*)d_in[1], (const T*)d_in[15], (const T*)d_in[16], xln1
  oproj_ln<bf16><<<dim3(B_ * NT_), 256, 0, stream>>>(ARGS_O(bf16));
  oproj_ln<float><<<dim3(B_ * NT_), 256, 0, stream>>>(ARGS_O(float));

#define ARGS_M(T, OP) xln1, (const T*)d_in[17], (const T*)d_in[18], (const T*)d_in[19], (const T*)d_in[20], (const T*)d_in[21], (const T*)d_in[22], OP + OFF_X
  mlp_fused<bf16><<<dim3(B_ * NT_), 256, 0, stream>>>(ARGS_M(bf16, outb));
  mlp_fused<float><<<dim3(B_ * NT_), 256, 0, stream>>>(ARGS_M(float, outf));

  // LAST: rel_emb overwrites the scratch region
#define ARGS_REL(T, OP) (const T*)d_in[2], (const T*)d_in[12], (const T*)d_in[13], OP + OFF_REL
  rpe_rel_kernel<bf16><<<dim3((B_ * NT_ * NS_) / 256), 256, 0, stream>>>(ARGS_REL(bf16, outb));
  rpe_rel_kernel<float><<<dim3((B_ * NT_ * NS_) / 256), 256, 0, stream>>>(ARGS_REL(float, outf));
}